// Round 6
// baseline (1183.909 us; speedup 1.0000x reference)
//
#include <hip/hip_runtime.h>

#define BATCH   512
#define GB      4                    // batches per group (MFMA D-rows)
#define GRP     2                    // phase-shifted groups per block
#define NBLK    (BATCH / (GB * GRP)) // 64 blocks, 4 waves each
#define TSTEPS  3600
#define XCHUNK  8
#define NCHUNK  (TSTEPS / XCHUNK)    // 450
#define H       64
#define CLASSES 5

typedef _Float16 half8 __attribute__((ext_vector_type(8)));
typedef float    f32x4 __attribute__((ext_vector_type(4)));

#define L2E 1.44269504088896f
#define S_N (2.0f * L2E)

__device__ __forceinline__ half8 bc_h8(uint4 v) { return __builtin_bit_cast(half8, v); }

// TWO PHASE-SHIFTED BATCH-GROUPS per block. R4's step is a serial ring:
// tail(110) -> write -> barrier(45) -> ds_read(140) -> mfma(60) -> tail.
// The read+barrier sit on the path because only one recurrence is in
// flight. Here the same 4 waves interleave two independent groups of 4
// batches: while group0 runs mfma+tail, group1's A-read is in flight
// (issued right after the previous barrier, consumed a full ~200cyc phase
// later), and vice versa -> LDS latency off the path. Unlike R3's in-wave
// unroll, per-phase issue count is unchanged; group1's instructions fill
// R4's STALL cycles. Barriers are raw lgkmcnt(0)+s_barrier (NOT
// __syncthreads: its vmcnt(0) drain would expose the global x-load
// latency every step). Every ds_read completes before the next drain
// (phase > LDS latency), so no exposed waits. Per-group math = R4
// exactly (chained MFMA, C-operand projections, fma tail).
__global__ __launch_bounds__(256, 1) void gru_mfma_kernel(
    const float* __restrict__ x,      // [B, T, 1]
    const float* __restrict__ w_ih,   // [192, 1]
    const float* __restrict__ w_hh,   // [192, 64]
    const float* __restrict__ b_ih,   // [192]
    const float* __restrict__ b_hh,   // [192]
    const float* __restrict__ w_head, // [5, 64]
    const float* __restrict__ b_head, // [5]
    float* __restrict__ out)          // [B, 5]
{
    // per group: [2 parities][4 batches x 80 f16] (batch stride 160B)
    __shared__ __align__(16) _Float16 hB[GRP][2][GB * 80];
    __shared__ float hf[GRP * GB][H];

    const int tid  = threadIdx.x;
    const int w    = tid >> 6;        // wave id: gate tiles {w, 4+w, 8+w}
    const int lane = tid & 63;
    const int q    = lane >> 4;       // batch-within-group (D rows 4q..4q+3)
    const int col  = lane & 15;       // tile column
    const int b0   = blockIdx.x * (GB * GRP);
    const int i    = 16 * w + col;    // this lane's hidden index

    // --- B fragments: gate tiles {w, 4+w, 8+w}, f16, exp2-pre-scaled
    // (shared by both groups).
    half8 wR[2], wZ[2], wN[2];
#pragma unroll
    for (int c = 0; c < 2; ++c) {
        const float* pr = w_hh + (16 * w       + col) * H + 32 * c + 8 * q;
        const float* pz = w_hh + (16 * (4 + w) + col) * H + 32 * c + 8 * q;
        const float* pn = w_hh + (16 * (8 + w) + col) * H + 32 * c + 8 * q;
        half8 fr, fz, fn;
#pragma unroll
        for (int j = 0; j < 8; ++j) {
            fr[j] = (_Float16)(-L2E * pr[j]);
            fz[j] = (_Float16)(-L2E * pz[j]);
            fn[j] = (_Float16)( S_N * pn[j]);
        }
        wR[c] = fr; wZ[c] = fz; wN[c] = fn;
    }

    const float bn = S_N * b_hh[2 * H + i];
    const f32x4 Cn = {bn, bn, bn, bn};
    const f32x4 Z  = {0.f, 0.f, 0.f, 0.f};
    f32x4 Cr0 = Z, Cz0 = Z, Cr1 = Z, Cz1 = Z;   // elem 0 rewritten per phase

    const float wih_r = -L2E * w_ih[i];
    const float wih_z = -L2E * w_ih[H + i];
    const float wih_n =  S_N * w_ih[2 * H + i];
    const float bsr = -L2E * (b_ih[i] + b_hh[i]);
    const float bsz = -L2E * (b_ih[H + i] + b_hh[H + i]);
    const float bin =  S_N * b_ih[2 * H + i];

    // LDS byte offsets (within a parity region)
    char* hb0 = (char*)&hB[0][0][0];
    char* hb1 = (char*)&hB[1][0][0];
    const int rdA0 = (col >> 2) * 160 + q * 16;  // A0: batch col>>2, k-octet q
    const int rdA1 = rdA0 + 64;                  // A1: k = 32+8q..+7
    const int wrH  = q * 160 + i * 2;            // write: batch q, value i

    *(_Float16*)(hb0 + wrH) = (_Float16)0.0f;    // h0 = 0, parity 0
    *(_Float16*)(hb1 + wrH) = (_Float16)0.0f;
    __syncthreads();

    // x: lane serves batch b0+4g+q; chunk held in 2x f32x4 per group
    const float* xq0 = x + (size_t)(b0 + q)      * TSTEPS;
    const float* xq1 = x + (size_t)(b0 + GB + q) * TSTEPS;
    f32x4 c00 = *(const f32x4*)(xq0), c01 = *(const f32x4*)(xq0 + 4);
    f32x4 c10 = *(const f32x4*)(xq1), c11 = *(const f32x4*)(xq1 + 4);

    float h0 = 0.0f, hm10 = -1.0f, h1 = 0.0f, hm11 = -1.0f;

    // prologue A-reads, parity 0 (latency exposed once)
    uint4 a00 = *(const uint4*)(hb0 + rdA0);
    uint4 a01 = *(const uint4*)(hb0 + rdA1);
    uint4 a10 = *(const uint4*)(hb1 + rdA0);
    uint4 a11 = *(const uint4*)(hb1 + rdA1);

#define PHASE(hb, aA, aB, CrV, CzV, hreg, hm1, XT, PW) {                       \
    const float xt_ = (XT);                                                    \
    CrV[0] = fmaf(xt_, wih_r, bsr);                                            \
    CzV[0] = fmaf(xt_, wih_z, bsz);                                            \
    const float inc_ = fmaf(xt_, wih_n, bin);                                  \
    const half8 A0_ = bc_h8(aA), A1_ = bc_h8(aB);                              \
    f32x4 dr_ = __builtin_amdgcn_mfma_f32_16x16x32_f16(A0_, wR[0], CrV, 0,0,0);\
    dr_ = __builtin_amdgcn_mfma_f32_16x16x32_f16(A1_, wR[1], dr_, 0,0,0);      \
    f32x4 dn_ = __builtin_amdgcn_mfma_f32_16x16x32_f16(A0_, wN[0], Cn, 0,0,0); \
    dn_ = __builtin_amdgcn_mfma_f32_16x16x32_f16(A1_, wN[1], dn_, 0,0,0);      \
    f32x4 dz_ = __builtin_amdgcn_mfma_f32_16x16x32_f16(A0_, wZ[0], CzV, 0,0,0);\
    dz_ = __builtin_amdgcn_mfma_f32_16x16x32_f16(A1_, wZ[1], dz_, 0,0,0);      \
    const float er_ = __builtin_amdgcn_exp2f(dr_[0]);                          \
    const float rr_ = __builtin_amdgcn_rcpf(1.0f + er_);                       \
    const float ev_ = __builtin_amdgcn_exp2f(fmaf(rr_, dn_[0], inc_));         \
    const float uu_ = __builtin_amdgcn_rcpf(ev_ + 1.0f);                       \
    const float nn_ = fmaf(-2.0f, uu_, 1.0f);        /* tanh */                \
    const float ss_ = fmaf(2.0f, uu_, hm1);          /* h-1+2u */              \
    const float ez_ = __builtin_amdgcn_exp2f(dz_[0]);                          \
    const float zg_ = __builtin_amdgcn_rcpf(1.0f + ez_);                       \
    hreg = fmaf(zg_, ss_, nn_);                      /* zh + (1-z)n */         \
    hm1  = hreg - 1.0f;                                                        \
    *(_Float16*)((hb) + (PW) + wrH) = (_Float16)hreg;                          \
    asm volatile("s_waitcnt lgkmcnt(0)" ::: "memory");                         \
    __builtin_amdgcn_s_barrier();                                              \
    asm volatile("" ::: "memory");                                             \
    aA = *(const uint4*)((hb) + (PW) + rdA0);   /* next-step prefetch */       \
    aB = *(const uint4*)((hb) + (PW) + rdA1);                                  \
}

#define STEP2(tt, X0, X1)                                                      \
    PHASE(hb0, a00, a01, Cr0, Cz0, h0, hm10, X0, ((((tt) & 1) ^ 1) * 640))     \
    PHASE(hb1, a10, a11, Cr1, Cz1, h1, hm11, X1, ((((tt) & 1) ^ 1) * 640))

    for (int tc = 0; tc < NCHUNK; ++tc) {
        const int nb = (tc + 1 < NCHUNK) ? (tc + 1) * XCHUNK : 0;
        const f32x4 n00 = *(const f32x4*)(xq0 + nb);
        const f32x4 n01 = *(const f32x4*)(xq0 + nb + 4);
        const f32x4 n10 = *(const f32x4*)(xq1 + nb);
        const f32x4 n11 = *(const f32x4*)(xq1 + nb + 4);

        STEP2(0, c00[0], c10[0])
        STEP2(1, c00[1], c10[1])
        STEP2(2, c00[2], c10[2])
        STEP2(3, c00[3], c10[3])
        STEP2(4, c01[0], c11[0])
        STEP2(5, c01[1], c11[1])
        STEP2(6, c01[2], c11[2])
        STEP2(7, c01[3], c11[3])

        c00 = n00; c01 = n01; c10 = n10; c11 = n11;
    }
#undef STEP2
#undef PHASE

    // ---- head: wave w reduces batches {b0+w, b0+4+w} ----
    hf[q][i]      = h0;               // group 0 -> rows 0..3
    hf[GB + q][i] = h1;               // group 1 -> rows 4..7
    __syncthreads();
#pragma unroll
    for (int gg = 0; gg < GRP; ++gg) {
        const float hv = hf[gg * GB + w][lane];
#pragma unroll
        for (int cc = 0; cc < CLASSES; ++cc) {
            float v = hv * w_head[cc * H + lane];
#pragma unroll
            for (int off = 32; off > 0; off >>= 1)
                v += __shfl_down(v, off, 64);
            if (lane == 0) out[(b0 + gg * GB + w) * CLASSES + cc] = v + b_head[cc];
        }
    }
}

extern "C" void kernel_launch(void* const* d_in, const int* in_sizes, int n_in,
                              void* d_out, int out_size, void* d_ws, size_t ws_size,
                              hipStream_t stream) {
    const float* x      = (const float*)d_in[0];
    const float* w_ih   = (const float*)d_in[1];
    const float* w_hh   = (const float*)d_in[2];
    const float* b_ih   = (const float*)d_in[3];
    const float* b_hh   = (const float*)d_in[4];
    const float* w_head = (const float*)d_in[5];
    const float* b_head = (const float*)d_in[6];
    float* out = (float*)d_out;

    gru_mfma_kernel<<<NBLK, 256, 0, stream>>>(x, w_ih, w_hh, b_ih, b_hh,
                                              w_head, b_head, out);
}

// Round 7
// 859.047 us; speedup vs baseline: 1.3782x; 1.3782x over previous
//
#include <hip/hip_runtime.h>

#define BATCH   512
#define GB      4                    // batches per block, carried on MFMA D-rows
#define NBLK    (BATCH / GB)         // 128 blocks, 4 waves each -> 1 wave/SIMD
#define TSTEPS  3600
#define H       64
#define XCHUNK  16
#define NCHUNK  (TSTEPS / XCHUNK)    // 225
#define CLASSES 5

typedef _Float16 half8 __attribute__((ext_vector_type(8)));
typedef float    f32x4 __attribute__((ext_vector_type(4)));

#define L2E 1.44269504088896f
#define S_N (2.0f * L2E)

__device__ __forceinline__ half8 bc_h8(uint4 v) { return __builtin_bit_cast(half8, v); }

// R4 (722us, best) + ONE change: per-step __syncthreads -> raw
// s_waitcnt lgkmcnt(0) + s_barrier. __syncthreads also drains vmcnt(0),
// which exposes the freshly-issued x-chunk global loads at the first
// barrier after each chunk boundary (~300-800 cyc raw, ~20-50/step
// amortized). The raw barrier keeps them in flight across all 16 steps;
// the compiler's vmcnt-before-use covers the actual consumption. Race
// safety (validated by R5/R6 running this exact pattern): each wave's
// parity-p reads are drained by its own lgkmcnt(0) BEFORE barrier_t, so
// when any wave proceeds to step t+1 and overwrites parity p, no reader
// remains. R3/R5/R6 lessons kept: no in-wave batch unroll (issue floor),
// no K-half split (accumulator pressure), chained MFMA, batches on MFMA
// D-rows, projections in the MFMA C operand, x in per-lane registers.
__global__ __launch_bounds__(256, 1) void gru_mfma_kernel(
    const float* __restrict__ x,      // [B, T, 1]
    const float* __restrict__ w_ih,   // [192, 1]
    const float* __restrict__ w_hh,   // [192, 64]
    const float* __restrict__ b_ih,   // [192]
    const float* __restrict__ b_hh,   // [192]
    const float* __restrict__ w_head, // [5, 64]
    const float* __restrict__ b_head, // [5]
    float* __restrict__ out)          // [B, 5]
{
    // [parity][batch*80 f16]: batch stride 160B, parity stride 640B
    __shared__ __align__(16) _Float16 hB[2][GB * 80];
    __shared__ float hf[GB][H];

    const int tid  = threadIdx.x;
    const int w    = tid >> 6;        // wave id: gate tiles {w, 4+w, 8+w}
    const int lane = tid & 63;
    const int q    = lane >> 4;       // this lane's BATCH (D rows 4q..4q+3)
    const int col  = lane & 15;       // tile column
    const int b0   = blockIdx.x * GB;
    const int i    = 16 * w + col;    // this lane's hidden index

    // --- B fragments: gate tiles {w, 4+w, 8+w}, f16, exp2-pre-scaled.
    half8 wR[2], wZ[2], wN[2];
#pragma unroll
    for (int c = 0; c < 2; ++c) {
        const float* pr = w_hh + (16 * w       + col) * H + 32 * c + 8 * q;
        const float* pz = w_hh + (16 * (4 + w) + col) * H + 32 * c + 8 * q;
        const float* pn = w_hh + (16 * (8 + w) + col) * H + 32 * c + 8 * q;
        half8 fr, fz, fn;
#pragma unroll
        for (int j = 0; j < 8; ++j) {
            fr[j] = (_Float16)(-L2E * pr[j]);
            fz[j] = (_Float16)(-L2E * pz[j]);
            fn[j] = (_Float16)( S_N * pn[j]);
        }
        wR[c] = fr; wZ[c] = fz; wN[c] = fn;
    }

    const float bn = S_N * b_hh[2 * H + i];
    const f32x4 Cn = {bn, bn, bn, bn};   // n bias rides the MFMA C operand
    const f32x4 Z  = {0.f, 0.f, 0.f, 0.f};
    f32x4 CrV = Z, CzV = Z;              // elem 0 rewritten per step (row 4q)

    const float wih_r = -L2E * w_ih[i];
    const float wih_z = -L2E * w_ih[H + i];
    const float wih_n =  S_N * w_ih[2 * H + i];
    const float bsr = -L2E * (b_ih[i] + b_hh[i]);
    const float bsz = -L2E * (b_ih[H + i] + b_hh[H + i]);
    const float bin =  S_N * b_ih[2 * H + i];

    // LDS byte offsets (within a parity region)
    char* hbase = (char*)&hB[0][0];
    const int rdA0 = (col >> 2) * 160 + q * 16;  // A0: batch col>>2, k=8q..8q+7
    const int rdA1 = rdA0 + 64;                  // A1: k=32+8q..32+8q+7
    const int wrH  = q * 160 + i * 2;            // write: batch q, value i

    *(_Float16*)(hbase + wrH) = (_Float16)0.0f;  // h0 = 0 (parity 0)
    __syncthreads();

    // x staging: lane's batch q chunk held in 4x f32x4, one chunk prefetched
    const float* xq = x + (size_t)(b0 + q) * TSTEPS;
    f32x4 xe0, xe1, xe2, xe3, xo0, xo1, xo2, xo3;
    xe0 = *(const f32x4*)(xq);      xe1 = *(const f32x4*)(xq + 4);
    xe2 = *(const f32x4*)(xq + 8);  xe3 = *(const f32x4*)(xq + 12);

    float h_reg = 0.0f, hm1 = -1.0f;

#define STEP(tt, XT) {                                                         \
    const int pr_ = ((tt) & 1) * 640;                                          \
    const int pw_ = (((tt) & 1) ^ 1) * 640;                                    \
    const uint4 a0 = *(const uint4*)(hbase + pr_ + rdA0);                      \
    const uint4 a1 = *(const uint4*)(hbase + pr_ + rdA1);                      \
    const float xt_ = (XT);                                                    \
    CrV[0] = fmaf(xt_, wih_r, bsr);     /* under ds_read shadow */             \
    CzV[0] = fmaf(xt_, wih_z, bsz);                                            \
    const float inc = fmaf(xt_, wih_n, bin);                                   \
    const half8 A0 = bc_h8(a0), A1 = bc_h8(a1);                                \
    f32x4 dr = __builtin_amdgcn_mfma_f32_16x16x32_f16(A0, wR[0], CrV, 0,0,0);  \
    dr = __builtin_amdgcn_mfma_f32_16x16x32_f16(A1, wR[1], dr, 0,0,0);         \
    f32x4 dn = __builtin_amdgcn_mfma_f32_16x16x32_f16(A0, wN[0], Cn, 0,0,0);   \
    dn = __builtin_amdgcn_mfma_f32_16x16x32_f16(A1, wN[1], dn, 0,0,0);         \
    f32x4 dz = __builtin_amdgcn_mfma_f32_16x16x32_f16(A0, wZ[0], CzV, 0,0,0);  \
    dz = __builtin_amdgcn_mfma_f32_16x16x32_f16(A1, wZ[1], dz, 0,0,0);         \
    const float er = __builtin_amdgcn_exp2f(dr[0]);                            \
    const float rr = __builtin_amdgcn_rcpf(1.0f + er);                         \
    const float ev = __builtin_amdgcn_exp2f(fmaf(rr, dn[0], inc));             \
    const float uu = __builtin_amdgcn_rcpf(ev + 1.0f);                         \
    const float nn = fmaf(-2.0f, uu, 1.0f);     /* tanh */                     \
    const float ss = fmaf(2.0f, uu, hm1);       /* h-1+2u */                   \
    const float ez = __builtin_amdgcn_exp2f(dz[0]);                            \
    const float zg = __builtin_amdgcn_rcpf(1.0f + ez);                         \
    h_reg = fmaf(zg, ss, nn);                   /* zh + (1-z)n */              \
    hm1 = h_reg - 1.0f;                                                        \
    *(_Float16*)(hbase + pw_ + wrH) = (_Float16)h_reg;                         \
    asm volatile("s_waitcnt lgkmcnt(0)" ::: "memory");                         \
    __builtin_amdgcn_s_barrier();                                              \
    asm volatile("" ::: "memory"); }

#define STEPS16(V0, V1, V2, V3)                                                \
    STEP(0,  V0[0]) STEP(1,  V0[1]) STEP(2,  V0[2]) STEP(3,  V0[3])            \
    STEP(4,  V1[0]) STEP(5,  V1[1]) STEP(6,  V1[2]) STEP(7,  V1[3])            \
    STEP(8,  V2[0]) STEP(9,  V2[1]) STEP(10, V2[2]) STEP(11, V2[3])            \
    STEP(12, V3[0]) STEP(13, V3[1]) STEP(14, V3[2]) STEP(15, V3[3])

    for (int tc = 0; tc < NCHUNK; ++tc) {
        const float* nx = xq + ((tc + 1 < NCHUNK) ? (tc + 1) * XCHUNK : 0);
        if ((tc & 1) == 0) {
            xo0 = *(const f32x4*)(nx);      xo1 = *(const f32x4*)(nx + 4);
            xo2 = *(const f32x4*)(nx + 8);  xo3 = *(const f32x4*)(nx + 12);
            STEPS16(xe0, xe1, xe2, xe3)
        } else {
            xe0 = *(const f32x4*)(nx);      xe1 = *(const f32x4*)(nx + 4);
            xe2 = *(const f32x4*)(nx + 8);  xe3 = *(const f32x4*)(nx + 12);
            STEPS16(xo0, xo1, xo2, xo3)
        }
    }
#undef STEPS16
#undef STEP

    // ---- head: wave w reduces batch w ----
    hf[q][i] = h_reg;                 // 256 threads cover 4x64 slots
    __syncthreads();
    {
        const float hv = hf[w][lane];
#pragma unroll
        for (int cc = 0; cc < CLASSES; ++cc) {
            float v = hv * w_head[cc * H + lane];
#pragma unroll
            for (int off = 32; off > 0; off >>= 1)
                v += __shfl_down(v, off, 64);
            if (lane == 0) out[(b0 + w) * CLASSES + cc] = v + b_head[cc];
        }
    }
}

extern "C" void kernel_launch(void* const* d_in, const int* in_sizes, int n_in,
                              void* d_out, int out_size, void* d_ws, size_t ws_size,
                              hipStream_t stream) {
    const float* x      = (const float*)d_in[0];
    const float* w_ih   = (const float*)d_in[1];
    const float* w_hh   = (const float*)d_in[2];
    const float* b_ih   = (const float*)d_in[3];
    const float* b_hh   = (const float*)d_in[4];
    const float* w_head = (const float*)d_in[5];
    const float* b_head = (const float*)d_in[6];
    float* out = (float*)d_out;

    gru_mfma_kernel<<<NBLK, 256, 0, stream>>>(x, w_ih, w_hh, b_ih, b_hh,
                                              w_head, b_head, out);
}

// Round 8
// 837.715 us; speedup vs baseline: 1.4133x; 1.0255x over previous
//
#include <hip/hip_runtime.h>

#define BATCH   512
#define GB      4                    // batches per block, carried on MFMA D-rows
#define NBLK    (BATCH / GB)         // 128 blocks, 4 waves each -> 1 wave/SIMD
#define TSTEPS  3600
#define H       64
#define XCHUNK  16
#define NCHUNK  (TSTEPS / XCHUNK)    // 225
#define CLASSES 5

typedef _Float16 half8 __attribute__((ext_vector_type(8)));
typedef float    f32x4 __attribute__((ext_vector_type(4)));

#define L2E 1.44269504088896f
#define S_N (2.0f * L2E)

__device__ __forceinline__ half8 bc_h8(uint4 v) { return __builtin_bit_cast(half8, v); }

// CHAMPION (R4, 722us) — reverted after R5/R7 bracketed it:
//   R5 (K-half MFMA split):        +34 cyc/step (accumulator pressure,
//                                   adds on the r-path)
//   R7 (raw lgkm+s_barrier):       +91 cyc/step (asm fences defeat compiler
//                                   scheduling; vmcnt-drain theory falsified)
//   R3 (in-wave batch unroll):     x2.7 (wave in-order issue serializes)
//   R6 (2 phase-shifted groups):   regression (same-wave issue floor +
//                                   CU halving)
// Structure: 4 waves/block, wave w computes gate tiles {w,4+w,8+w}; 4
// batches ride the MFMA D-rows (A[m][k]=h_{m>>2}[k]) so 6 MFMAs serve 4
// batches and each lane's tail is ONE cell (batch q=lane>>4, hidden
// i=16w+col). h exchanged through double-buffered LDS (parity via
// unrolled tt), one __syncthreads per step. The step is a serial ring:
// write -> barrier -> ds_read -> mfma chain -> tail -> write (~482 cyc),
// latency-bound (HBM 0.07%, MfmaUtil 8.6%); read-ahead is impossible
// (recurrence), so the LDS+barrier latency is structural. exp2-pre-scaled
// weights (no runtime log2e muls), n-bias + r/z input projections ride
// the MFMA C operand (projections computed under the ds_read shadow),
// x in per-lane registers one chunk ahead (compile-time indexing only).
__global__ __launch_bounds__(256, 1) void gru_mfma_kernel(
    const float* __restrict__ x,      // [B, T, 1]
    const float* __restrict__ w_ih,   // [192, 1]
    const float* __restrict__ w_hh,   // [192, 64]
    const float* __restrict__ b_ih,   // [192]
    const float* __restrict__ b_hh,   // [192]
    const float* __restrict__ w_head, // [5, 64]
    const float* __restrict__ b_head, // [5]
    float* __restrict__ out)          // [B, 5]
{
    // [parity][batch*80 f16]: batch stride 160B, parity stride 640B
    __shared__ __align__(16) _Float16 hB[2][GB * 80];
    __shared__ float hf[GB][H];

    const int tid  = threadIdx.x;
    const int w    = tid >> 6;        // wave id: gate tiles {w, 4+w, 8+w}
    const int lane = tid & 63;
    const int q    = lane >> 4;       // this lane's BATCH (D rows 4q..4q+3)
    const int col  = lane & 15;       // tile column
    const int b0   = blockIdx.x * GB;
    const int i    = 16 * w + col;    // this lane's hidden index

    // --- B fragments: gate tiles {w, 4+w, 8+w}, f16, exp2-pre-scaled.
    half8 wR[2], wZ[2], wN[2];
#pragma unroll
    for (int c = 0; c < 2; ++c) {
        const float* pr = w_hh + (16 * w       + col) * H + 32 * c + 8 * q;
        const float* pz = w_hh + (16 * (4 + w) + col) * H + 32 * c + 8 * q;
        const float* pn = w_hh + (16 * (8 + w) + col) * H + 32 * c + 8 * q;
        half8 fr, fz, fn;
#pragma unroll
        for (int j = 0; j < 8; ++j) {
            fr[j] = (_Float16)(-L2E * pr[j]);
            fz[j] = (_Float16)(-L2E * pz[j]);
            fn[j] = (_Float16)( S_N * pn[j]);
        }
        wR[c] = fr; wZ[c] = fz; wN[c] = fn;
    }

    const float bn = S_N * b_hh[2 * H + i];
    const f32x4 Cn = {bn, bn, bn, bn};   // n bias rides the MFMA C operand
    const f32x4 Z  = {0.f, 0.f, 0.f, 0.f};
    f32x4 CrV = Z, CzV = Z;              // elem 0 rewritten per step (row 4q)

    const float wih_r = -L2E * w_ih[i];
    const float wih_z = -L2E * w_ih[H + i];
    const float wih_n =  S_N * w_ih[2 * H + i];
    const float bsr = -L2E * (b_ih[i] + b_hh[i]);
    const float bsz = -L2E * (b_ih[H + i] + b_hh[H + i]);
    const float bin =  S_N * b_ih[2 * H + i];

    // LDS byte offsets (within a parity region)
    char* hbase = (char*)&hB[0][0];
    const int rdA0 = (col >> 2) * 160 + q * 16;  // A0: batch col>>2, k=8q..8q+7
    const int rdA1 = rdA0 + 64;                  // A1: k=32+8q..32+8q+7
    const int wrH  = q * 160 + i * 2;            // write: batch q, value i

    *(_Float16*)(hbase + wrH) = (_Float16)0.0f;  // h0 = 0 (parity 0)
    __syncthreads();

    // x staging: lane's batch q chunk held in 4x f32x4, one chunk prefetched
    const float* xq = x + (size_t)(b0 + q) * TSTEPS;
    f32x4 xe0, xe1, xe2, xe3, xo0, xo1, xo2, xo3;
    xe0 = *(const f32x4*)(xq);      xe1 = *(const f32x4*)(xq + 4);
    xe2 = *(const f32x4*)(xq + 8);  xe3 = *(const f32x4*)(xq + 12);

    float h_reg = 0.0f, hm1 = -1.0f;

#define STEP(tt, XT) {                                                         \
    const int pr_ = ((tt) & 1) * 640;                                          \
    const int pw_ = (((tt) & 1) ^ 1) * 640;                                    \
    const uint4 a0 = *(const uint4*)(hbase + pr_ + rdA0);                      \
    const uint4 a1 = *(const uint4*)(hbase + pr_ + rdA1);                      \
    const float xt_ = (XT);                                                    \
    CrV[0] = fmaf(xt_, wih_r, bsr);     /* under ds_read shadow */             \
    CzV[0] = fmaf(xt_, wih_z, bsz);                                            \
    const float inc = fmaf(xt_, wih_n, bin);                                   \
    const half8 A0 = bc_h8(a0), A1 = bc_h8(a1);                                \
    f32x4 dr = __builtin_amdgcn_mfma_f32_16x16x32_f16(A0, wR[0], CrV, 0,0,0);  \
    dr = __builtin_amdgcn_mfma_f32_16x16x32_f16(A1, wR[1], dr, 0,0,0);         \
    f32x4 dn = __builtin_amdgcn_mfma_f32_16x16x32_f16(A0, wN[0], Cn, 0,0,0);   \
    dn = __builtin_amdgcn_mfma_f32_16x16x32_f16(A1, wN[1], dn, 0,0,0);         \
    f32x4 dz = __builtin_amdgcn_mfma_f32_16x16x32_f16(A0, wZ[0], CzV, 0,0,0);  \
    dz = __builtin_amdgcn_mfma_f32_16x16x32_f16(A1, wZ[1], dz, 0,0,0);         \
    const float er = __builtin_amdgcn_exp2f(dr[0]);                            \
    const float rr = __builtin_amdgcn_rcpf(1.0f + er);                         \
    const float ev = __builtin_amdgcn_exp2f(fmaf(rr, dn[0], inc));             \
    const float uu = __builtin_amdgcn_rcpf(ev + 1.0f);                         \
    const float nn = fmaf(-2.0f, uu, 1.0f);     /* tanh */                     \
    const float ss = fmaf(2.0f, uu, hm1);       /* h-1+2u */                   \
    const float ez = __builtin_amdgcn_exp2f(dz[0]);                            \
    const float zg = __builtin_amdgcn_rcpf(1.0f + ez);                         \
    h_reg = fmaf(zg, ss, nn);                   /* zh + (1-z)n */              \
    hm1 = h_reg - 1.0f;                                                        \
    *(_Float16*)(hbase + pw_ + wrH) = (_Float16)h_reg;                         \
    __syncthreads(); }

#define STEPS16(V0, V1, V2, V3)                                                \
    STEP(0,  V0[0]) STEP(1,  V0[1]) STEP(2,  V0[2]) STEP(3,  V0[3])            \
    STEP(4,  V1[0]) STEP(5,  V1[1]) STEP(6,  V1[2]) STEP(7,  V1[3])            \
    STEP(8,  V2[0]) STEP(9,  V2[1]) STEP(10, V2[2]) STEP(11, V2[3])            \
    STEP(12, V3[0]) STEP(13, V3[1]) STEP(14, V3[2]) STEP(15, V3[3])

    for (int tc = 0; tc < NCHUNK; ++tc) {
        const float* nx = xq + ((tc + 1 < NCHUNK) ? (tc + 1) * XCHUNK : 0);
        if ((tc & 1) == 0) {
            xo0 = *(const f32x4*)(nx);      xo1 = *(const f32x4*)(nx + 4);
            xo2 = *(const f32x4*)(nx + 8);  xo3 = *(const f32x4*)(nx + 12);
            STEPS16(xe0, xe1, xe2, xe3)
        } else {
            xe0 = *(const f32x4*)(nx);      xe1 = *(const f32x4*)(nx + 4);
            xe2 = *(const f32x4*)(nx + 8);  xe3 = *(const f32x4*)(nx + 12);
            STEPS16(xo0, xo1, xo2, xo3)
        }
    }
#undef STEPS16
#undef STEP

    // ---- head: wave w reduces batch w ----
    hf[q][i] = h_reg;                 // 256 threads cover 4x64 slots
    __syncthreads();
    {
        const float hv = hf[w][lane];
#pragma unroll
        for (int cc = 0; cc < CLASSES; ++cc) {
            float v = hv * w_head[cc * H + lane];
#pragma unroll
            for (int off = 32; off > 0; off >>= 1)
                v += __shfl_down(v, off, 64);
            if (lane == 0) out[(b0 + w) * CLASSES + cc] = v + b_head[cc];
        }
    }
}

extern "C" void kernel_launch(void* const* d_in, const int* in_sizes, int n_in,
                              void* d_out, int out_size, void* d_ws, size_t ws_size,
                              hipStream_t stream) {
    const float* x      = (const float*)d_in[0];
    const float* w_ih   = (const float*)d_in[1];
    const float* w_hh   = (const float*)d_in[2];
    const float* b_ih   = (const float*)d_in[3];
    const float* b_hh   = (const float*)d_in[4];
    const float* w_head = (const float*)d_in[5];
    const float* b_head = (const float*)d_in[6];
    float* out = (float*)d_out;

    gru_mfma_kernel<<<NBLK, 256, 0, stream>>>(x, w_ih, w_hh, b_ih, b_hh,
                                              w_head, b_head, out);
}

// Round 9
// 766.104 us; speedup vs baseline: 1.5454x; 1.0935x over previous
//
#include <hip/hip_runtime.h>

#define BATCH   512
#define GB      4                    // batches per block, carried on MFMA D-rows
#define NBLK    (BATCH / GB)         // 128 blocks, 4 waves each -> 1 wave/SIMD
#define TSTEPS  3600
#define H       64
#define XCHUNK  16
#define NCHUNK  (TSTEPS / XCHUNK)    // 225
#define CLASSES 5

typedef _Float16 half8 __attribute__((ext_vector_type(8)));
typedef float    f32x4 __attribute__((ext_vector_type(4)));

#define L2E 1.44269504088896f
#define S_N (2.0f * L2E)

__device__ __forceinline__ half8 bc_h8(uint4 v) { return __builtin_bit_cast(half8, v); }

// R4-champion (722us) + K-half MFMA split. R8 ablation (same-base):
//   x-in-regs vs bpermute x:  +115 cyc/step  (32 live x-VGPRs degrade the
//                                             scheduled step body)
//   K-half split vs chained:   -53 cyc/step  (dependent-MFMA C-chain at the
//                                             head of the r->n->h tail
//                                             replaced by a 4-cyc VALU add)
//   raw barrier vs syncthreads:+22 cyc/step
// This kernel = round-3 kernel D verbatim (bpermute x, end-of-step
// projections, __syncthreads) with ONLY the MFMA section changed to
// independent K-half pairs (second half C=Z, add in tail).
// Structure recap: 4 waves/block, wave w owns gate tiles {w,4+w,8+w};
// 4 batches ride the MFMA D-rows (A[m][k]=h_{m>>2}[k]); each lane's tail
// is one cell (batch q=lane>>4, hidden i=16w+col); h exchanged via
// double-buffered LDS (parity by unrolled tt), one __syncthreads/step;
// exp2-pre-scaled weights; n-bias and r/z projections ride the MFMA C
// operand; x broadcast per step by one off-path ds_bpermute.
__global__ __launch_bounds__(256, 1) void gru_mfma_kernel(
    const float* __restrict__ x,      // [B, T, 1]
    const float* __restrict__ w_ih,   // [192, 1]
    const float* __restrict__ w_hh,   // [192, 64]
    const float* __restrict__ b_ih,   // [192]
    const float* __restrict__ b_hh,   // [192]
    const float* __restrict__ w_head, // [5, 64]
    const float* __restrict__ b_head, // [5]
    float* __restrict__ out)          // [B, 5]
{
    // [parity][batch*80 f16]: batch stride 160B, parity stride 640B
    __shared__ __align__(16) _Float16 hB[2][GB * 80];
    __shared__ float hf[GB][H];

    const int tid  = threadIdx.x;
    const int w    = tid >> 6;        // wave id: gate tiles {w, 4+w, 8+w}
    const int lane = tid & 63;
    const int q    = lane >> 4;       // this lane's BATCH (D rows 4q..4q+3)
    const int col  = lane & 15;       // tile column
    const int b0   = blockIdx.x * GB;
    const int i    = 16 * w + col;    // this lane's hidden index

    // --- B fragments: gate tiles {w, 4+w, 8+w}, f16, exp2-pre-scaled.
    half8 wR[2], wZ[2], wN[2];
#pragma unroll
    for (int c = 0; c < 2; ++c) {
        const float* pr = w_hh + (16 * w       + col) * H + 32 * c + 8 * q;
        const float* pz = w_hh + (16 * (4 + w) + col) * H + 32 * c + 8 * q;
        const float* pn = w_hh + (16 * (8 + w) + col) * H + 32 * c + 8 * q;
        half8 fr, fz, fn;
#pragma unroll
        for (int j = 0; j < 8; ++j) {
            fr[j] = (_Float16)(-L2E * pr[j]);
            fz[j] = (_Float16)(-L2E * pz[j]);
            fn[j] = (_Float16)( S_N * pn[j]);
        }
        wR[c] = fr; wZ[c] = fz; wN[c] = fn;
    }

    const float bn = S_N * b_hh[2 * H + i];
    f32x4 Cn = {bn, bn, bn, bn};     // n bias rides the MFMA C operand
    const f32x4 Z = {0.f, 0.f, 0.f, 0.f};
    f32x4 Cr = Z, Cz = Z;            // per-step: only element 0 updated

    const float wih_r = -L2E * w_ih[i];
    const float wih_z = -L2E * w_ih[H + i];
    const float wih_n =  S_N * w_ih[2 * H + i];
    const float bsr = -L2E * (b_ih[i] + b_hh[i]);
    const float bsz = -L2E * (b_ih[H + i] + b_hh[H + i]);
    const float bin =  S_N * b_ih[2 * H + i];

    // LDS byte offsets (within a parity region)
    char* hbase = (char*)&hB[0][0];
    const int rdA0 = (col >> 2) * 160 + q * 16;  // A0: batch col>>2, k=8q..8q+7
    const int rdA1 = rdA0 + 64;                  // A1: k=32+8q..32+8q+7
    const int wrH  = q * 160 + i * 2;            // write: batch q, value i

    *(_Float16*)(hbase + wrH) = (_Float16)0.0f;  // h0 = 0 (parity 0)
    __syncthreads();

    // x staging: lane (q,col) holds x[batch q][chunk, step col]
    const float* xq = x + (size_t)(b0 + q) * TSTEPS;
    float vx = xq[col];
    const int pbase = 64 * q;        // bpermute byte base: lane 16q

    // proj for step 0
    float xt0 = __builtin_bit_cast(float,
        __builtin_amdgcn_ds_bpermute(pbase, __builtin_bit_cast(int, vx)));
    float irc = fmaf(xt0, wih_r, bsr);
    float izc = fmaf(xt0, wih_z, bsz);
    float inc = fmaf(xt0, wih_n, bin);

    float h_reg = 0.0f, hm1 = -1.0f;

    for (int tc = 0; tc < NCHUNK; ++tc) {
        const int nb = (tc + 1 < NCHUNK) ? (tc + 1) * XCHUNK : 0;
        const float vxn = xq[nb + col];

#pragma unroll
        for (int tt = 0; tt < XCHUNK; ++tt) {
            const int pr_ = (tt & 1) * 640;          // read parity base
            const int pw_ = ((tt & 1) ^ 1) * 640;    // write parity base

            const uint4 a0 = *(const uint4*)(hbase + pr_ + rdA0);
            const uint4 a1 = *(const uint4*)(hbase + pr_ + rdA1);

            // next step's x (off the critical path; in-wave bpermute)
            const float xsrc = (tt == XCHUNK - 1) ? vxn : vx;
            const float xtn = __builtin_bit_cast(float,
                __builtin_amdgcn_ds_bpermute(pbase + 4 * ((tt + 1) & 15),
                                             __builtin_bit_cast(int, xsrc)));

            Cr[0] = irc;             // only row 4q / reg 0 is consumed
            Cz[0] = izc;

            const half8 A0 = bc_h8(a0);
            const half8 A1 = bc_h8(a1);
            // K-half split: independent pairs, add in tail (r pair first --
            // it heads the serial r->n->h tail)
            f32x4 r0, r1, n0, n1, z0, z1;
            r0 = __builtin_amdgcn_mfma_f32_16x16x32_f16(A0, wR[0], Cr, 0, 0, 0);
            r1 = __builtin_amdgcn_mfma_f32_16x16x32_f16(A1, wR[1], Z,  0, 0, 0);
            n0 = __builtin_amdgcn_mfma_f32_16x16x32_f16(A0, wN[0], Cn, 0, 0, 0);
            n1 = __builtin_amdgcn_mfma_f32_16x16x32_f16(A1, wN[1], Z,  0, 0, 0);
            z0 = __builtin_amdgcn_mfma_f32_16x16x32_f16(A0, wZ[0], Cz, 0, 0, 0);
            z1 = __builtin_amdgcn_mfma_f32_16x16x32_f16(A1, wZ[1], Z,  0, 0, 0);

            // tail: one cell per lane (batch q, hidden i)
            const float er = __builtin_amdgcn_exp2f(r0[0] + r1[0]);
            const float r  = __builtin_amdgcn_rcpf(1.0f + er);
            const float ev = __builtin_amdgcn_exp2f(fmaf(r, n0[0] + n1[0], inc));
            const float u  = __builtin_amdgcn_rcpf(ev + 1.0f);
            const float nn = fmaf(-2.0f, u, 1.0f);      // tanh
            const float s  = fmaf(2.0f, u, hm1);        // h-1+2u
            const float ez = __builtin_amdgcn_exp2f(z0[0] + z1[0]);
            const float zg = __builtin_amdgcn_rcpf(1.0f + ez);
            h_reg = fmaf(zg, s, nn);                    // zh + (1-z)n
            hm1   = h_reg - 1.0f;

            // next step's projections (off-path; reads THIS step's xtn)
            irc = fmaf(xtn, wih_r, bsr);
            izc = fmaf(xtn, wih_z, bsz);
            inc = fmaf(xtn, wih_n, bin);

            *(_Float16*)(hbase + pw_ + wrH) = (_Float16)h_reg;
            __syncthreads();
        }
        vx = vxn;
    }

    // ---- head: wave w reduces batch w ----
    hf[q][i] = h_reg;                 // 256 threads cover 4x64 slots
    __syncthreads();
    {
        const float hv = hf[w][lane];
#pragma unroll
        for (int cc = 0; cc < CLASSES; ++cc) {
            float v = hv * w_head[cc * H + lane];
#pragma unroll
            for (int off = 32; off > 0; off >>= 1)
                v += __shfl_down(v, off, 64);
            if (lane == 0) out[(b0 + w) * CLASSES + cc] = v + b_head[cc];
        }
    }
}

extern "C" void kernel_launch(void* const* d_in, const int* in_sizes, int n_in,
                              void* d_out, int out_size, void* d_ws, size_t ws_size,
                              hipStream_t stream) {
    const float* x      = (const float*)d_in[0];
    const float* w_ih   = (const float*)d_in[1];
    const float* w_hh   = (const float*)d_in[2];
    const float* b_ih   = (const float*)d_in[3];
    const float* b_hh   = (const float*)d_in[4];
    const float* w_head = (const float*)d_in[5];
    const float* b_head = (const float*)d_in[6];
    float* out = (float*)d_out;

    gru_mfma_kernel<<<NBLK, 256, 0, stream>>>(x, w_ih, w_hh, b_ih, b_hh,
                                              w_head, b_head, out);
}

// Round 10
// 719.189 us; speedup vs baseline: 1.6462x; 1.0652x over previous
//
#include <hip/hip_runtime.h>

#define BATCH   512
#define GB      4                    // batches per block, carried on MFMA D-rows
#define NBLK    (BATCH / GB)         // 128 blocks, 4 waves each -> 1 wave/SIMD
#define TSTEPS  3600
#define H       64
#define XCHUNK  16
#define NCHUNK  (TSTEPS / XCHUNK)    // 225
#define CLASSES 5

typedef _Float16 half8 __attribute__((ext_vector_type(8)));
typedef float    f32x4 __attribute__((ext_vector_type(4)));

#define L2E 1.44269504088896f
#define S_N (2.0f * L2E)

__device__ __forceinline__ half8 bc_h8(uint4 v) { return __builtin_bit_cast(half8, v); }

// CHAMPION RESTORE — round-3 kernel verbatim (benched 722us, dispatch
// ~701us, 467 cyc/step). Session ablation summary (all vs this base):
//   in-wave batch unroll   x2.7   (wave in-order issue serializes)
//   2 phase-shifted groups +67%   (same-wave issue floor + CU halving)
//   bpermute h-exchange    +14%   (8 DS ops > 1 write + 2 reads)
//   raw lgkm+s_barrier     +5%    (asm fences defeat compiler scheduling)
//   K-half MFMA split      +3%    (on this base; -6% on x-in-regs base --
//                                  factors are NOT additive, scheduler
//                                  re-layout dominates at the +/-5% level)
//   x-in-regs (32 VGPRs)   +16%   (degrades the scheduled step body)
// Structure: 4 waves/block, wave w owns gate tiles {w,4+w,8+w}; 4 batches
// ride the MFMA D-rows (A[m][k]=h_{m>>2}[k]) so 6 MFMAs serve 4 batches;
// each lane's tail is ONE cell (batch q=lane>>4, hidden i=16w+col);
// h exchanged via double-buffered LDS (parity by unrolled tt), one
// __syncthreads per step. Step = serial ring write->barrier->read->mfma->
// tail (~467 cyc), latency-bound (HBM 0.07%, MfmaUtil ~10%): read-ahead
// is impossible (recurrence), so LDS RT + barrier + tail chain are
// structural. exp2-pre-scaled weights; n-bias and r/z projections ride
// the MFMA C operand (computed off-path at end of prior step); x
// broadcast per step by one off-path ds_bpermute.
__global__ __launch_bounds__(256, 1) void gru_mfma_kernel(
    const float* __restrict__ x,      // [B, T, 1]
    const float* __restrict__ w_ih,   // [192, 1]
    const float* __restrict__ w_hh,   // [192, 64]
    const float* __restrict__ b_ih,   // [192]
    const float* __restrict__ b_hh,   // [192]
    const float* __restrict__ w_head, // [5, 64]
    const float* __restrict__ b_head, // [5]
    float* __restrict__ out)          // [B, 5]
{
    // [parity][batch*80 f16]: batch stride 160B, parity stride 640B
    __shared__ __align__(16) _Float16 hB[2][GB * 80];
    __shared__ float hf[GB][H];

    const int tid  = threadIdx.x;
    const int w    = tid >> 6;        // wave id: gate tiles {w, 4+w, 8+w}
    const int lane = tid & 63;
    const int q    = lane >> 4;       // this lane's BATCH (D rows 4q..4q+3)
    const int col  = lane & 15;       // tile column
    const int b0   = blockIdx.x * GB;
    const int i    = 16 * w + col;    // this lane's hidden index

    // --- B fragments: gate tiles {w, 4+w, 8+w}, f16, exp2-pre-scaled.
    half8 wR[2], wZ[2], wN[2];
#pragma unroll
    for (int c = 0; c < 2; ++c) {
        const float* pr = w_hh + (16 * w       + col) * H + 32 * c + 8 * q;
        const float* pz = w_hh + (16 * (4 + w) + col) * H + 32 * c + 8 * q;
        const float* pn = w_hh + (16 * (8 + w) + col) * H + 32 * c + 8 * q;
        half8 fr, fz, fn;
#pragma unroll
        for (int j = 0; j < 8; ++j) {
            fr[j] = (_Float16)(-L2E * pr[j]);
            fz[j] = (_Float16)(-L2E * pz[j]);
            fn[j] = (_Float16)( S_N * pn[j]);
        }
        wR[c] = fr; wZ[c] = fz; wN[c] = fn;
    }

    const float bn = S_N * b_hh[2 * H + i];
    f32x4 Cn = {bn, bn, bn, bn};     // n bias rides the MFMA C chain
    const f32x4 Z = {0.f, 0.f, 0.f, 0.f};
    f32x4 Cr = Z, Cz = Z;            // per-step: only element 0 updated

    const float wih_r = -L2E * w_ih[i];
    const float wih_z = -L2E * w_ih[H + i];
    const float wih_n =  S_N * w_ih[2 * H + i];
    const float bsr = -L2E * (b_ih[i] + b_hh[i]);
    const float bsz = -L2E * (b_ih[H + i] + b_hh[H + i]);
    const float bin =  S_N * b_ih[2 * H + i];

    // LDS byte offsets (within a parity region)
    char* hbase = (char*)&hB[0][0];
    const int rdA0 = (col >> 2) * 160 + q * 16;  // A0: batch col>>2, k=8q..8q+7
    const int rdA1 = rdA0 + 64;                  // A1: k=32+8q..32+8q+7
    const int wrH  = q * 160 + i * 2;            // write: batch q, value i

    *(_Float16*)(hbase + wrH) = (_Float16)0.0f;  // h0 = 0 (parity 0)
    __syncthreads();

    // x staging: lane (q,col) holds x[batch q][chunk, step col]
    const float* xq = x + (size_t)(b0 + q) * TSTEPS;
    float vx = xq[col];
    const int pbase = 64 * q;        // bpermute byte base: lane 16q

    // proj for step 0
    float xt0 = __builtin_bit_cast(float,
        __builtin_amdgcn_ds_bpermute(pbase, __builtin_bit_cast(int, vx)));
    float irc = fmaf(xt0, wih_r, bsr);
    float izc = fmaf(xt0, wih_z, bsz);
    float inc = fmaf(xt0, wih_n, bin);

    float h_reg = 0.0f, hm1 = -1.0f;

    for (int tc = 0; tc < NCHUNK; ++tc) {
        const int nb = (tc + 1 < NCHUNK) ? (tc + 1) * XCHUNK : 0;
        const float vxn = xq[nb + col];

#pragma unroll
        for (int tt = 0; tt < XCHUNK; ++tt) {
            const int pr_ = (tt & 1) * 640;          // read parity base
            const int pw_ = ((tt & 1) ^ 1) * 640;    // write parity base

            const uint4 a0 = *(const uint4*)(hbase + pr_ + rdA0);
            const uint4 a1 = *(const uint4*)(hbase + pr_ + rdA1);

            // next step's x (off the critical path; in-wave bpermute)
            const float xsrc = (tt == XCHUNK - 1) ? vxn : vx;
            const float xtn = __builtin_bit_cast(float,
                __builtin_amdgcn_ds_bpermute(pbase + 4 * ((tt + 1) & 15),
                                             __builtin_bit_cast(int, xsrc)));

            Cr[0] = irc;             // only row 4q / reg 0 is consumed
            Cz[0] = izc;

            const half8 A0 = bc_h8(a0);
            const half8 A1 = bc_h8(a1);
            f32x4 dr, dn, dz;
            dr = __builtin_amdgcn_mfma_f32_16x16x32_f16(A0, wR[0], Cr, 0, 0, 0);
            dr = __builtin_amdgcn_mfma_f32_16x16x32_f16(A1, wR[1], dr, 0, 0, 0);
            dn = __builtin_amdgcn_mfma_f32_16x16x32_f16(A0, wN[0], Cn, 0, 0, 0);
            dn = __builtin_amdgcn_mfma_f32_16x16x32_f16(A1, wN[1], dn, 0, 0, 0);
            dz = __builtin_amdgcn_mfma_f32_16x16x32_f16(A0, wZ[0], Cz, 0, 0, 0);
            dz = __builtin_amdgcn_mfma_f32_16x16x32_f16(A1, wZ[1], dz, 0, 0, 0);

            // tail: one cell per lane (batch q, hidden i)
            const float er = __builtin_amdgcn_exp2f(dr[0]);
            const float r  = __builtin_amdgcn_rcpf(1.0f + er);
            const float ev = __builtin_amdgcn_exp2f(fmaf(r, dn[0], inc));
            const float u  = __builtin_amdgcn_rcpf(ev + 1.0f);
            const float nn = fmaf(-2.0f, u, 1.0f);      // tanh
            const float s  = fmaf(2.0f, u, hm1);        // h-1+2u
            const float ez = __builtin_amdgcn_exp2f(dz[0]);
            const float zg = __builtin_amdgcn_rcpf(1.0f + ez);
            h_reg = fmaf(zg, s, nn);                    // zh + (1-z)n
            hm1   = h_reg - 1.0f;

            // next step's projections (off-path; reads THIS step's xtn)
            irc = fmaf(xtn, wih_r, bsr);
            izc = fmaf(xtn, wih_z, bsz);
            inc = fmaf(xtn, wih_n, bin);

            *(_Float16*)(hbase + pw_ + wrH) = (_Float16)h_reg;
            __syncthreads();
        }
        vx = vxn;
    }

    // ---- head: wave w reduces batch w ----
    hf[q][i] = h_reg;                 // 256 threads cover 4x64 slots
    __syncthreads();
    {
        const float hv = hf[w][lane];
#pragma unroll
        for (int cc = 0; cc < CLASSES; ++cc) {
            float v = hv * w_head[cc * H + lane];
#pragma unroll
            for (int off = 32; off > 0; off >>= 1)
                v += __shfl_down(v, off, 64);
            if (lane == 0) out[(b0 + w) * CLASSES + cc] = v + b_head[cc];
        }
    }
}

extern "C" void kernel_launch(void* const* d_in, const int* in_sizes, int n_in,
                              void* d_out, int out_size, void* d_ws, size_t ws_size,
                              hipStream_t stream) {
    const float* x      = (const float*)d_in[0];
    const float* w_ih   = (const float*)d_in[1];
    const float* w_hh   = (const float*)d_in[2];
    const float* b_ih   = (const float*)d_in[3];
    const float* b_hh   = (const float*)d_in[4];
    const float* w_head = (const float*)d_in[5];
    const float* b_head = (const float*)d_in[6];
    float* out = (float*)d_out;

    gru_mfma_kernel<<<NBLK, 256, 0, stream>>>(x, w_ih, w_hh, b_ih, b_hh,
                                              w_head, b_head, out);
}